// Round 8
// baseline (292.354 us; speedup 1.0000x reference)
//
#include <hip/hip_runtime.h>
#include <hip/hip_bf16.h>

#define HID 128

typedef __attribute__((ext_vector_type(8))) short bf16x8;
typedef __attribute__((ext_vector_type(4))) float f32x4;

__device__ inline unsigned short f2bf(float f) {
    unsigned u = __float_as_uint(f);
    u += 0x7fffu + ((u >> 16) & 1u);   // RNE
    return (unsigned short)(u >> 16);
}
__device__ inline float bfval(unsigned short s) {
    return __uint_as_float(((unsigned)s) << 16);
}

// ---------------- CSR build ----------------

__global__ void deg_init_kernel(int* deg, int N) {
    int i = blockIdx.x * blockDim.x + threadIdx.x;
    if (i < N) deg[i] = 1;  // self loop
}

__global__ void deg_count_kernel(const int* __restrict__ dst, int E, int* deg) {
    int i = blockIdx.x * blockDim.x + threadIdx.x;
    if (i < E) atomicAdd(&deg[dst[i]], 1);
}

__global__ __launch_bounds__(256) void scan1_kernel(const int* __restrict__ deg,
                                                    int* __restrict__ bsum, int N) {
    int tid = threadIdx.x;
    int i = blockIdx.x * 256 + tid;
    int v = (i < N) ? deg[i] : 0;
    #pragma unroll
    for (int off = 1; off < 64; off <<= 1) v += __shfl_xor(v, off);
    __shared__ int ws[4];
    if ((tid & 63) == 0) ws[tid >> 6] = v;
    __syncthreads();
    if (tid == 0) bsum[blockIdx.x] = ws[0] + ws[1] + ws[2] + ws[3];
}

__global__ __launch_bounds__(256) void scan2_kernel(const int* __restrict__ bsum,
                                                    int* __restrict__ boff,
                                                    int* __restrict__ row_ptr, int NB, int N) {
    __shared__ int s[256];
    int tid = threadIdx.x;
    int v = (tid < NB) ? bsum[tid] : 0;
    s[tid] = v;
    __syncthreads();
    for (int off = 1; off < 256; off <<= 1) {
        int t = (tid >= off) ? s[tid - off] : 0;
        __syncthreads();
        s[tid] += t;
        __syncthreads();
    }
    if (tid < NB) boff[tid] = s[tid] - v;  // exclusive
    if (tid == NB - 1) row_ptr[N] = s[tid];
}

__global__ __launch_bounds__(256) void scan3_kernel(const int* __restrict__ deg,
                                                    const int* __restrict__ boff,
                                                    int* __restrict__ row_ptr,
                                                    int* __restrict__ cursor,
                                                    int* __restrict__ col, int N) {
    __shared__ int s[256];
    int tid = threadIdx.x;
    int i = blockIdx.x * 256 + tid;
    int d = (i < N) ? deg[i] : 0;
    s[tid] = d;
    __syncthreads();
    for (int off = 1; off < 256; off <<= 1) {
        int t = (tid >= off) ? s[tid - off] : 0;
        __syncthreads();
        s[tid] += t;
        __syncthreads();
    }
    if (i < N) {
        int run = boff[blockIdx.x] + s[tid] - d;  // exclusive prefix
        row_ptr[i] = run;
        cursor[i] = run + 1;  // slot 0 taken by self loop
        col[run] = i;         // self loop
    }
}

__global__ void scatter_kernel(const int* __restrict__ src, const int* __restrict__ dst,
                               int E, int* cursor, int* col, int* posarr) {
    int i = blockIdx.x * blockDim.x + threadIdx.x;
    if (i < E) {
        int pos = atomicAdd(&cursor[dst[i]], 1);
        col[pos] = src[i];
        posarr[i] = pos;
    }
}

// ---------------- prep: W -> MFMA frag layout, hi/lo split ----------------
// wbuf[layer][p][s][t][lane][j]  (ushort), p=0: bf16(W), p=1: bf16(W - hi)
// frag element j for lane l: k = s*32 + (l>>4)*8 + j, c = t*16 + (l&15)
__global__ void prep_w_kernel(const float* __restrict__ W1, const float* __restrict__ W2,
                              const float* __restrict__ W3, ushort* __restrict__ wbuf) {
    int t = blockIdx.x * blockDim.x + threadIdx.x;   // 0 .. 3*4096-1
    if (t >= 3 * 4096) return;
    int layer = t >> 12;
    int rem = t & 4095;
    int lane = rem & 63;
    int tt = (rem >> 6) & 7;
    int s = (rem >> 9) & 3;
    int p = rem >> 11;
    const float* W = (layer == 0) ? W1 : (layer == 1) ? W2 : W3;
    int k0 = s * 32 + (lane >> 4) * 8;
    int c = tt * 16 + (lane & 15);
    ushort out[8];
    #pragma unroll
    for (int j = 0; j < 8; ++j) {
        float w = W[(size_t)(k0 + j) * HID + c];
        unsigned short hi = f2bf(w);
        out[j] = (p == 0) ? hi : f2bf(w - bfval(hi));
    }
    size_t base = (size_t)layer * 32768 + ((((size_t)p * 4 + s) * 8 + tt) * 64 + lane) * 8;
    *(uint4*)&wbuf[base] = *(uint4*)out;
}

// ---------------- MFMA GEMM + fused alphas (register-resident W) ----------------
template <int H, bool SRC32>
__global__ __launch_bounds__(256) void mfma_gemm_kernel(const void* __restrict__ xin,
                                                        const ushort* __restrict__ wbuf,
                                                        const float* __restrict__ a_src,
                                                        const float* __restrict__ a_dst,
                                                        ushort* __restrict__ h,
                                                        float* __restrict__ pa_out,
                                                        float* __restrict__ pd_out, int N) {
    __shared__ float part[4][64][2];   // used only for H==1 cross-wave alpha combine
    int tid = threadIdx.x;
    int wv = tid >> 6, lane = tid & 63;
    int r0 = blockIdx.x * 64;
    int cg = lane >> 4;          // k-group / channel-group
    int lr = lane & 15;          // row-in-group

    // W frags for this wave's two tiles
    bf16x8 wf[2][4][2];          // [p][s][tt]
    #pragma unroll
    for (int p = 0; p < 2; ++p)
        #pragma unroll
        for (int s = 0; s < 4; ++s)
            #pragma unroll
            for (int tt = 0; tt < 2; ++tt)
                wf[p][s][tt] = *(const bf16x8*)&wbuf[((((p * 4 + s) * 8) + 2 * wv + tt) * 64 + lane) * 8];

    // x frags: rows r0 + rg*16 + lr, k = cg*8 + s*32 + j
    bf16x8 xf[4][4];             // [rg][s]
    #pragma unroll
    for (int rg = 0; rg < 4; ++rg) {
        int row = r0 + rg * 16 + lr;
        if (row >= N) row = N - 1;
        if (SRC32) {
            const float* xp = &((const float*)xin)[(size_t)row * HID + cg * 8];
            #pragma unroll
            for (int s = 0; s < 4; ++s) {
                float4 a = *(const float4*)&xp[s * 32];
                float4 b = *(const float4*)&xp[s * 32 + 4];
                ushort u[8] = {f2bf(a.x), f2bf(a.y), f2bf(a.z), f2bf(a.w),
                               f2bf(b.x), f2bf(b.y), f2bf(b.z), f2bf(b.w)};
                xf[rg][s] = *(bf16x8*)u;
            }
        } else {
            const ushort* xp = &((const ushort*)xin)[(size_t)row * HID + cg * 8];
            #pragma unroll
            for (int s = 0; s < 4; ++s) xf[rg][s] = *(const bf16x8*)&xp[s * 32];
        }
    }

    f32x4 acc[4][2];             // [rg][tt]
    #pragma unroll
    for (int rg = 0; rg < 4; ++rg)
        #pragma unroll
        for (int tt = 0; tt < 2; ++tt) acc[rg][tt] = (f32x4){0.f, 0.f, 0.f, 0.f};

    #pragma unroll
    for (int rg = 0; rg < 4; ++rg)
        #pragma unroll
        for (int p = 0; p < 2; ++p)
            #pragma unroll
            for (int s = 0; s < 4; ++s)
                #pragma unroll
                for (int tt = 0; tt < 2; ++tt)
                    acc[rg][tt] = __builtin_amdgcn_mfma_f32_16x16x32_bf16(
                        wf[p][s][tt], xf[rg][s], acc[rg][tt], 0, 0, 0);

    // epilogue: D col(lane&15)=row, D row(cg*4+j)=channel within tile 2wv+tt
    #pragma unroll
    for (int rg = 0; rg < 4; ++rg) {
        int row = r0 + rg * 16 + lr;
        bool ok = row < N;
        if (ok) {
            #pragma unroll
            for (int tt = 0; tt < 2; ++tt) {
                uint2 pk;
                pk.x = (unsigned)f2bf(acc[rg][tt][0]) | ((unsigned)f2bf(acc[rg][tt][1]) << 16);
                pk.y = (unsigned)f2bf(acc[rg][tt][2]) | ((unsigned)f2bf(acc[rg][tt][3]) << 16);
                *(uint2*)&h[(size_t)row * HID + (2 * wv + tt) * 16 + cg * 4] = pk;
            }
        }
        float sa = 0.f, sd = 0.f;
        #pragma unroll
        for (int tt = 0; tt < 2; ++tt) {
            int ch = (2 * wv + tt) * 16 + cg * 4;
            float4 av = *(const float4*)&a_src[ch];
            float4 dv = *(const float4*)&a_dst[ch];
            sa += acc[rg][tt][0] * av.x + acc[rg][tt][1] * av.y +
                  acc[rg][tt][2] * av.z + acc[rg][tt][3] * av.w;
            sd += acc[rg][tt][0] * dv.x + acc[rg][tt][1] * dv.y +
                  acc[rg][tt][2] * dv.z + acc[rg][tt][3] * dv.w;
        }
        sa += __shfl_xor(sa, 16); sa += __shfl_xor(sa, 32);
        sd += __shfl_xor(sd, 16); sd += __shfl_xor(sd, 32);
        if (H == 4) {
            if (ok && cg == 0) {
                pa_out[(size_t)row * 4 + wv] = sa;
                pd_out[(size_t)row * 4 + wv] = sd;
            }
        } else {
            if (lane < 16) {
                part[wv][rg * 16 + lr][0] = sa;
                part[wv][rg * 16 + lr][1] = sd;
            }
        }
    }
    if (H == 1) {
        __syncthreads();
        if (tid < 128) {
            int r = tid >> 1, c = tid & 1;
            float v = part[0][r][c] + part[1][r][c] + part[2][r][c] + part[3][r][c];
            int row = r0 + r;
            if (row < N) {
                if (c) pd_out[row] = v; else pa_out[row] = v;
            }
        }
    }
}

// ---------------- A: per-edge scores (coalesced, edge-parallel) ----------------
// ids [0,E): real edges; ids [E,E+N): self loops. esc[pos*H + h] = leaky(pa[src]+pd[dst])
template <int H>
__global__ void edge_score_kernel(const int* __restrict__ srcv, const int* __restrict__ dstv,
                                  const int* __restrict__ posarr, const int* __restrict__ rp,
                                  const float* __restrict__ pa, const float* __restrict__ pd,
                                  float* __restrict__ esc, int E, int N) {
    int id = blockIdx.x * blockDim.x + threadIdx.x;
    if (id >= E + N) return;
    int src, dst, pos;
    if (id < E) { src = srcv[id]; dst = dstv[id]; pos = posarr[id]; }
    else        { src = dst = id - E; pos = rp[src]; }
    if (H == 4) {
        float4 a = *(const float4*)&pa[(size_t)src * 4];
        float4 d = *(const float4*)&pd[(size_t)dst * 4];
        float4 e;
        e.x = a.x + d.x; e.x = (e.x >= 0.f) ? e.x : 0.2f * e.x;
        e.y = a.y + d.y; e.y = (e.y >= 0.f) ? e.y : 0.2f * e.y;
        e.z = a.z + d.z; e.z = (e.z >= 0.f) ? e.z : 0.2f * e.z;
        e.w = a.w + d.w; e.w = (e.w >= 0.f) ? e.w : 0.2f * e.w;
        *(float4*)&esc[(size_t)pos * 4] = e;
    } else {
        float e = pa[src] + pd[dst];
        esc[pos] = (e >= 0.f) ? e : 0.2f * e;
    }
}

// ---------------- B: per-node softmax, rewrite esc in place as alpha ----------------
// wave per node; lane reads esc[base*H + lane] (coalesced).
template <int H>
__global__ __launch_bounds__(256) void softmax_norm_kernel(const int* __restrict__ rp,
                                                           float* __restrict__ esc, int N) {
    int lane = threadIdx.x & 63;
    int node = blockIdx.x * 4 + (threadIdx.x >> 6);
    if (node >= N) return;
    int start = rp[node], end = rp[node + 1];
    constexpr int EPC = 64 / H;
    int eidx = lane / H;
    float m = -INFINITY, denom = 0.f;
    for (int base = start; base < end; base += EPC) {
        bool valid = (base + eidx) < end;
        float e = valid ? esc[(size_t)base * H + lane] : -INFINITY;
        float cmax = e;
        #pragma unroll
        for (int off = H; off < 64; off <<= 1) cmax = fmaxf(cmax, __shfl_xor(cmax, off));
        float nm = fmaxf(m, cmax);
        float p = valid ? __expf(e - nm) : 0.f;
        float csum = p;
        #pragma unroll
        for (int off = H; off < 64; off <<= 1) csum += __shfl_xor(csum, off);
        denom = denom * __expf(m - nm) + csum;
        m = nm;
    }
    float inv = 1.f / denom;
    for (int base = start; base < end; base += EPC) {
        if ((base + eidx) < end) {
            float e = esc[(size_t)base * H + lane];
            esc[(size_t)base * H + lane] = __expf(e - m) * inv;
        }
    }
}

// ---------------- C: slice gather (XCD-L2-resident h column slice) ----------------
// blockIdx & 3 = slice (32 channels); XCD = blockIdx % 8 -> slice s pinned to XCDs {s, s+4}:
// per-XCD h working set = 50000 x 64B = 3.2 MB < 4 MiB L2.
// wave = 4 nodes x 4 edge-slots x 4 chan-quads; lane = nd*16 + slot*4 + c4.
template <int H, bool RELU, bool OUTBF>
__global__ __launch_bounds__(256) void slice_gather_kernel(const ushort* __restrict__ h,
                                                           const float* __restrict__ esc,
                                                           const int* __restrict__ rp,
                                                           const int* __restrict__ col,
                                                           const float* __restrict__ bias,
                                                           void* __restrict__ outv, int N) {
    int s  = blockIdx.x & 3;
    int ng = blockIdx.x >> 2;
    int wv = threadIdx.x >> 6, lane = threadIdx.x & 63;
    int nd   = lane >> 4;
    int slot = (lane >> 2) & 3;
    int c4   = lane & 3;
    int node = ng * 16 + wv * 4 + nd;
    if (node >= N) return;
    int start = rp[node], end = rp[node + 1];
    constexpr int HS = (H == 4) ? 1 : 0;   // hsel = s for H==4 else 0

    float acc[8] = {0.f, 0.f, 0.f, 0.f, 0.f, 0.f, 0.f, 0.f};
    #pragma unroll 2
    for (int base = start; base < end; base += 4) {
        int idx = base + slot;
        if (idx < end) {
            int src = col[idx];
            float al = esc[(size_t)idx * H + (HS ? s : 0)];
            uint4 hv = *(const uint4*)&h[(size_t)src * HID + s * 32 + c4 * 8];
            acc[0] += al * __uint_as_float(hv.x << 16);
            acc[1] += al * __uint_as_float(hv.x & 0xffff0000u);
            acc[2] += al * __uint_as_float(hv.y << 16);
            acc[3] += al * __uint_as_float(hv.y & 0xffff0000u);
            acc[4] += al * __uint_as_float(hv.z << 16);
            acc[5] += al * __uint_as_float(hv.z & 0xffff0000u);
            acc[6] += al * __uint_as_float(hv.w << 16);
            acc[7] += al * __uint_as_float(hv.w & 0xffff0000u);
        }
    }
    // combine over slot (lane bits [3:2])
    #pragma unroll
    for (int off = 4; off <= 8; off <<= 1) {
        #pragma unroll
        for (int k = 0; k < 8; ++k) acc[k] += __shfl_xor(acc[k], off);
    }
    if (slot == 0) {
        int ch = s * 32 + c4 * 8;
        float o[8];
        #pragma unroll
        for (int k = 0; k < 8; ++k) {
            o[k] = acc[k] + bias[ch + k];
            if (RELU) o[k] = fmaxf(o[k], 0.f);
        }
        if (OUTBF) {
            uint4 ov;
            ov.x = (unsigned)f2bf(o[0]) | ((unsigned)f2bf(o[1]) << 16);
            ov.y = (unsigned)f2bf(o[2]) | ((unsigned)f2bf(o[3]) << 16);
            ov.z = (unsigned)f2bf(o[4]) | ((unsigned)f2bf(o[5]) << 16);
            ov.w = (unsigned)f2bf(o[6]) | ((unsigned)f2bf(o[7]) << 16);
            *(uint4*)&((ushort*)outv)[(size_t)node * HID + ch] = ov;
        } else {
            float* op = &((float*)outv)[(size_t)node * HID + ch];
            *(float4*)op = make_float4(o[0], o[1], o[2], o[3]);
            *(float4*)(op + 4) = make_float4(o[4], o[5], o[6], o[7]);
        }
    }
}

// ---------------- launch ----------------

extern "C" void kernel_launch(void* const* d_in, const int* in_sizes, int n_in,
                              void* d_out, int out_size, void* d_ws, size_t ws_size,
                              hipStream_t stream) {
    const float* x   = (const float*)d_in[0];
    const int*   ei  = (const int*)d_in[1];
    const float* W1  = (const float*)d_in[2];
    const float* as1 = (const float*)d_in[3];
    const float* ad1 = (const float*)d_in[4];
    const float* b1  = (const float*)d_in[5];
    const float* W2  = (const float*)d_in[6];
    const float* as2 = (const float*)d_in[7];
    const float* ad2 = (const float*)d_in[8];
    const float* b2  = (const float*)d_in[9];
    const float* W3  = (const float*)d_in[10];
    const float* as3 = (const float*)d_in[11];
    const float* ad3 = (const float*)d_in[12];
    const float* b3  = (const float*)d_in[13];

    int N = in_sizes[0] / HID;
    int E = in_sizes[1] / 2;
    const int* srcv = ei;
    const int* dstv = ei + E;

    char* ws = (char*)d_ws;
    size_t ofs = 0;
    auto alloc = [&](size_t bytes) -> void* {
        void* p = ws + ofs;
        ofs = (ofs + bytes + 255) & ~(size_t)255;
        return p;
    };
    int NB = (N + 255) / 256;
    int*    rp   = (int*)alloc((size_t)(N + 1) * 4);
    int*    cur  = (int*)alloc((size_t)N * 4);
    int*    deg  = (int*)alloc((size_t)N * 4);
    int*    bsum = (int*)alloc((size_t)NB * 4);
    int*    boff = (int*)alloc((size_t)NB * 4);
    int*    col  = (int*)alloc((size_t)(E + N) * 4);
    int*    posa = (int*)alloc((size_t)E * 4);
    ushort* ys   = (ushort*)alloc((size_t)N * HID * 2);   // layer-1 out (bf16)
    ushort* zs   = (ushort*)alloc((size_t)N * HID * 2);   // layer-2 out (bf16)
    ushort* hb   = (ushort*)alloc((size_t)N * HID * 2);   // per-layer h (bf16)
    ushort* wbuf = (ushort*)alloc((size_t)3 * 32768 * 2); // W frag layout (hi+lo) x3
    float*  pa   = (float*)alloc((size_t)N * 4 * 4);
    float*  pd   = (float*)alloc((size_t)N * 4 * 4);
    float*  esc  = (float*)alloc((size_t)(E + N) * 4 * 4);

    // CSR build
    deg_init_kernel<<<(N + 255) / 256, 256, 0, stream>>>(deg, N);
    deg_count_kernel<<<(E + 255) / 256, 256, 0, stream>>>(dstv, E, deg);
    scan1_kernel<<<NB, 256, 0, stream>>>(deg, bsum, N);
    scan2_kernel<<<1, 256, 0, stream>>>(bsum, boff, rp, NB, N);
    scan3_kernel<<<NB, 256, 0, stream>>>(deg, boff, rp, cur, col, N);
    scatter_kernel<<<(E + 255) / 256, 256, 0, stream>>>(srcv, dstv, E, cur, col, posa);

    prep_w_kernel<<<(3 * 4096 + 255) / 256, 256, 0, stream>>>(W1, W2, W3, wbuf);

    int gGemm  = (N + 63) / 64;
    int gEdge  = (E + N + 255) / 256;
    int gNode  = (N + 3) / 4;
    int gSlice = ((N + 15) / 16) * 4;

    // layer 1 (4 heads, relu): fp32 x in
    mfma_gemm_kernel<4, true><<<gGemm, 256, 0, stream>>>(x, wbuf, as1, ad1, hb, pa, pd, N);
    edge_score_kernel<4><<<gEdge, 256, 0, stream>>>(srcv, dstv, posa, rp, pa, pd, esc, E, N);
    softmax_norm_kernel<4><<<gNode, 256, 0, stream>>>(rp, esc, N);
    slice_gather_kernel<4, true, true><<<gSlice, 256, 0, stream>>>(hb, esc, rp, col, b1, ys, N);
    // layer 2 (4 heads, relu)
    mfma_gemm_kernel<4, false><<<gGemm, 256, 0, stream>>>(ys, wbuf + 32768, as2, ad2, hb, pa, pd, N);
    edge_score_kernel<4><<<gEdge, 256, 0, stream>>>(srcv, dstv, posa, rp, pa, pd, esc, E, N);
    softmax_norm_kernel<4><<<gNode, 256, 0, stream>>>(rp, esc, N);
    slice_gather_kernel<4, true, true><<<gSlice, 256, 0, stream>>>(hb, esc, rp, col, b2, zs, N);
    // layer 3 (1 head, no relu) -> d_out fp32
    mfma_gemm_kernel<1, false><<<gGemm, 256, 0, stream>>>(zs, wbuf + 65536, as3, ad3, hb, pa, pd, N);
    edge_score_kernel<1><<<gEdge, 256, 0, stream>>>(srcv, dstv, posa, rp, pa, pd, esc, E, N);
    softmax_norm_kernel<1><<<gNode, 256, 0, stream>>>(rp, esc, N);
    slice_gather_kernel<1, false, false><<<gSlice, 256, 0, stream>>>(hb, esc, rp, col, b3, d_out, N);
}

// Round 9
// 220.121 us; speedup vs baseline: 1.3282x; 1.3282x over previous
//
#include <hip/hip_runtime.h>
#include <hip/hip_bf16.h>

#define HID 128

typedef __attribute__((ext_vector_type(8))) short bf16x8;
typedef __attribute__((ext_vector_type(4))) float f32x4;

__device__ inline unsigned short f2bf(float f) {
    unsigned u = __float_as_uint(f);
    u += 0x7fffu + ((u >> 16) & 1u);   // RNE
    return (unsigned short)(u >> 16);
}
__device__ inline float bfval(unsigned short s) {
    return __uint_as_float(((unsigned)s) << 16);
}

// ---------------- CSR build ----------------

__global__ void deg_init_kernel(int* deg, int N) {
    int i = blockIdx.x * blockDim.x + threadIdx.x;
    if (i < N) deg[i] = 1;  // self loop
}

__global__ void deg_count_kernel(const int* __restrict__ dst, int E, int* deg) {
    int i = blockIdx.x * blockDim.x + threadIdx.x;
    if (i < E) atomicAdd(&deg[dst[i]], 1);
}

__global__ __launch_bounds__(256) void scan1_kernel(const int* __restrict__ deg,
                                                    int* __restrict__ bsum, int N) {
    int tid = threadIdx.x;
    int i = blockIdx.x * 256 + tid;
    int v = (i < N) ? deg[i] : 0;
    #pragma unroll
    for (int off = 1; off < 64; off <<= 1) v += __shfl_xor(v, off);
    __shared__ int ws[4];
    if ((tid & 63) == 0) ws[tid >> 6] = v;
    __syncthreads();
    if (tid == 0) bsum[blockIdx.x] = ws[0] + ws[1] + ws[2] + ws[3];
}

__global__ __launch_bounds__(256) void scan2_kernel(const int* __restrict__ bsum,
                                                    int* __restrict__ boff,
                                                    int* __restrict__ row_ptr, int NB, int N) {
    __shared__ int s[256];
    int tid = threadIdx.x;
    int v = (tid < NB) ? bsum[tid] : 0;
    s[tid] = v;
    __syncthreads();
    for (int off = 1; off < 256; off <<= 1) {
        int t = (tid >= off) ? s[tid - off] : 0;
        __syncthreads();
        s[tid] += t;
        __syncthreads();
    }
    if (tid < NB) boff[tid] = s[tid] - v;  // exclusive
    if (tid == NB - 1) row_ptr[N] = s[tid];
}

__global__ __launch_bounds__(256) void scan3_kernel(const int* __restrict__ deg,
                                                    const int* __restrict__ boff,
                                                    int* __restrict__ row_ptr,
                                                    int* __restrict__ cursor,
                                                    int* __restrict__ col, int N) {
    __shared__ int s[256];
    int tid = threadIdx.x;
    int i = blockIdx.x * 256 + tid;
    int d = (i < N) ? deg[i] : 0;
    s[tid] = d;
    __syncthreads();
    for (int off = 1; off < 256; off <<= 1) {
        int t = (tid >= off) ? s[tid - off] : 0;
        __syncthreads();
        s[tid] += t;
        __syncthreads();
    }
    if (i < N) {
        int run = boff[blockIdx.x] + s[tid] - d;  // exclusive prefix
        row_ptr[i] = run;
        cursor[i] = run + 1;  // slot 0 taken by self loop
        col[run] = i;         // self loop
    }
}

__global__ void scatter_kernel(const int* __restrict__ src, const int* __restrict__ dst,
                               int E, int* cursor, int* col) {
    int i = blockIdx.x * blockDim.x + threadIdx.x;
    if (i < E) {
        int pos = atomicAdd(&cursor[dst[i]], 1);
        col[pos] = src[i];
    }
}

// ---------------- prep: W -> MFMA frag layout, hi/lo split ----------------
// wbuf[layer][p][s][t][lane][j]  (ushort), p=0: bf16(W), p=1: bf16(W - hi)
// frag element j for lane l: k = s*32 + (l>>4)*8 + j, c = t*16 + (l&15)
__global__ void prep_w_kernel(const float* __restrict__ W1, const float* __restrict__ W2,
                              const float* __restrict__ W3, ushort* __restrict__ wbuf) {
    int t = blockIdx.x * blockDim.x + threadIdx.x;   // 0 .. 3*4096-1
    if (t >= 3 * 4096) return;
    int layer = t >> 12;
    int rem = t & 4095;
    int lane = rem & 63;
    int tt = (rem >> 6) & 7;
    int s = (rem >> 9) & 3;
    int p = rem >> 11;
    const float* W = (layer == 0) ? W1 : (layer == 1) ? W2 : W3;
    int k0 = s * 32 + (lane >> 4) * 8;
    int c = tt * 16 + (lane & 15);
    ushort out[8];
    #pragma unroll
    for (int j = 0; j < 8; ++j) {
        float w = W[(size_t)(k0 + j) * HID + c];
        unsigned short hi = f2bf(w);
        out[j] = (p == 0) ? hi : f2bf(w - bfval(hi));
    }
    size_t base = (size_t)layer * 32768 + ((((size_t)p * 4 + s) * 8 + tt) * 64 + lane) * 8;
    *(uint4*)&wbuf[base] = *(uint4*)out;
}

// ---------------- MFMA GEMM + fused alphas (register-resident W) ----------------
template <int H, bool SRC32>
__global__ __launch_bounds__(256) void mfma_gemm_kernel(const void* __restrict__ xin,
                                                        const ushort* __restrict__ wbuf,
                                                        const float* __restrict__ a_src,
                                                        const float* __restrict__ a_dst,
                                                        ushort* __restrict__ h,
                                                        float* __restrict__ pa_out,
                                                        float* __restrict__ pd_out, int N) {
    __shared__ float part[4][64][2];   // used only for H==1 cross-wave alpha combine
    int tid = threadIdx.x;
    int wv = tid >> 6, lane = tid & 63;
    int r0 = blockIdx.x * 64;
    int cg = lane >> 4;          // k-group / channel-group
    int lr = lane & 15;          // row-in-group

    // W frags for this wave's two tiles
    bf16x8 wf[2][4][2];          // [p][s][tt]
    #pragma unroll
    for (int p = 0; p < 2; ++p)
        #pragma unroll
        for (int s = 0; s < 4; ++s)
            #pragma unroll
            for (int tt = 0; tt < 2; ++tt)
                wf[p][s][tt] = *(const bf16x8*)&wbuf[((((p * 4 + s) * 8) + 2 * wv + tt) * 64 + lane) * 8];

    // x frags: rows r0 + rg*16 + lr, k = cg*8 + s*32 + j
    bf16x8 xf[4][4];             // [rg][s]
    #pragma unroll
    for (int rg = 0; rg < 4; ++rg) {
        int row = r0 + rg * 16 + lr;
        if (row >= N) row = N - 1;
        if (SRC32) {
            const float* xp = &((const float*)xin)[(size_t)row * HID + cg * 8];
            #pragma unroll
            for (int s = 0; s < 4; ++s) {
                float4 a = *(const float4*)&xp[s * 32];
                float4 b = *(const float4*)&xp[s * 32 + 4];
                ushort u[8] = {f2bf(a.x), f2bf(a.y), f2bf(a.z), f2bf(a.w),
                               f2bf(b.x), f2bf(b.y), f2bf(b.z), f2bf(b.w)};
                xf[rg][s] = *(bf16x8*)u;
            }
        } else {
            const ushort* xp = &((const ushort*)xin)[(size_t)row * HID + cg * 8];
            #pragma unroll
            for (int s = 0; s < 4; ++s) xf[rg][s] = *(const bf16x8*)&xp[s * 32];
        }
    }

    f32x4 acc[4][2];             // [rg][tt]
    #pragma unroll
    for (int rg = 0; rg < 4; ++rg)
        #pragma unroll
        for (int tt = 0; tt < 2; ++tt) acc[rg][tt] = (f32x4){0.f, 0.f, 0.f, 0.f};

    #pragma unroll
    for (int rg = 0; rg < 4; ++rg)
        #pragma unroll
        for (int p = 0; p < 2; ++p)
            #pragma unroll
            for (int s = 0; s < 4; ++s)
                #pragma unroll
                for (int tt = 0; tt < 2; ++tt)
                    acc[rg][tt] = __builtin_amdgcn_mfma_f32_16x16x32_bf16(
                        wf[p][s][tt], xf[rg][s], acc[rg][tt], 0, 0, 0);

    // epilogue: D col(lane&15)=row, D row(cg*4+j)=channel within tile 2wv+tt
    #pragma unroll
    for (int rg = 0; rg < 4; ++rg) {
        int row = r0 + rg * 16 + lr;
        bool ok = row < N;
        if (ok) {
            #pragma unroll
            for (int tt = 0; tt < 2; ++tt) {
                uint2 pk;
                pk.x = (unsigned)f2bf(acc[rg][tt][0]) | ((unsigned)f2bf(acc[rg][tt][1]) << 16);
                pk.y = (unsigned)f2bf(acc[rg][tt][2]) | ((unsigned)f2bf(acc[rg][tt][3]) << 16);
                *(uint2*)&h[(size_t)row * HID + (2 * wv + tt) * 16 + cg * 4] = pk;
            }
        }
        float sa = 0.f, sd = 0.f;
        #pragma unroll
        for (int tt = 0; tt < 2; ++tt) {
            int ch = (2 * wv + tt) * 16 + cg * 4;
            float4 av = *(const float4*)&a_src[ch];
            float4 dv = *(const float4*)&a_dst[ch];
            sa += acc[rg][tt][0] * av.x + acc[rg][tt][1] * av.y +
                  acc[rg][tt][2] * av.z + acc[rg][tt][3] * av.w;
            sd += acc[rg][tt][0] * dv.x + acc[rg][tt][1] * dv.y +
                  acc[rg][tt][2] * dv.z + acc[rg][tt][3] * dv.w;
        }
        sa += __shfl_xor(sa, 16); sa += __shfl_xor(sa, 32);
        sd += __shfl_xor(sd, 16); sd += __shfl_xor(sd, 32);
        if (H == 4) {
            if (ok && cg == 0) {
                pa_out[(size_t)row * 4 + wv] = sa;
                pd_out[(size_t)row * 4 + wv] = sd;
            }
        } else {
            if (lane < 16) {
                part[wv][rg * 16 + lr][0] = sa;
                part[wv][rg * 16 + lr][1] = sd;
            }
        }
    }
    if (H == 1) {
        __syncthreads();
        if (tid < 128) {
            int r = tid >> 1, c = tid & 1;
            float v = part[0][r][c] + part[1][r][c] + part[2][r][c] + part[3][r][c];
            int row = r0 + r;
            if (row < N) {
                if (c) pd_out[row] = v; else pa_out[row] = v;
            }
        }
    }
}

// ---------------- aggregation: wave per node, redundant in-lane scores ----------------
// lane = q*16 + cl: edge-slot q (0..3), channels cl*8..cl*8+7. Each lane computes its
// edge's score itself (no si/pi broadcasts); softmax stats reduce over q = 2 shfl_xor.
// 8 edges in flight per iteration (two slots per lane).
template <int H, bool RELU, bool OUTBF>
__global__ __launch_bounds__(256) void aggregate_kernel(const ushort* __restrict__ h,
                                                        const float* __restrict__ asrc,
                                                        const float* __restrict__ adst,
                                                        const int* __restrict__ rp,
                                                        const int* __restrict__ col,
                                                        const float* __restrict__ bias,
                                                        void* __restrict__ outv, int N) {
    int lane = threadIdx.x & 63;
    int node = blockIdx.x * 4 + (threadIdx.x >> 6);
    if (node >= N) return;
    int start = rp[node], end = rp[node + 1];
    int q  = lane >> 4;
    int cl = lane & 15;
    int ahd = (H == 4) ? (cl >> 2) : 0;
    float adst_n = adst[(size_t)node * H + ahd];

    float m = -INFINITY, den = 0.f;
    float acc[8] = {0.f, 0.f, 0.f, 0.f, 0.f, 0.f, 0.f, 0.f};

    #define ACC_EDGE(hv, pi)                                     \
        { acc[0] += pi * __uint_as_float(hv.x << 16);            \
          acc[1] += pi * __uint_as_float(hv.x & 0xffff0000u);    \
          acc[2] += pi * __uint_as_float(hv.y << 16);            \
          acc[3] += pi * __uint_as_float(hv.y & 0xffff0000u);    \
          acc[4] += pi * __uint_as_float(hv.z << 16);            \
          acc[5] += pi * __uint_as_float(hv.z & 0xffff0000u);    \
          acc[6] += pi * __uint_as_float(hv.w << 16);            \
          acc[7] += pi * __uint_as_float(hv.w & 0xffff0000u); }

    for (int base = start; base < end; base += 8) {
        int i1 = base + q, i2 = base + 4 + q;
        bool v1 = i1 < end, v2 = i2 < end;
        int s1 = v1 ? col[i1] : 0;
        int s2 = v2 ? col[i2] : 0;
        // issue h gathers early (independent of score math)
        uint4 h1, h2;
        if (v1) h1 = *(const uint4*)&h[(size_t)s1 * HID + cl * 8];
        if (v2) h2 = *(const uint4*)&h[(size_t)s2 * HID + cl * 8];
        float e1 = -INFINITY, e2 = -INFINITY;
        if (v1) { float t = asrc[(size_t)s1 * H + ahd] + adst_n; e1 = (t >= 0.f) ? t : 0.2f * t; }
        if (v2) { float t = asrc[(size_t)s2 * H + ahd] + adst_n; e2 = (t >= 0.f) ? t : 0.2f * t; }

        float cmax = fmaxf(e1, e2);
        cmax = fmaxf(cmax, __shfl_xor(cmax, 16));
        cmax = fmaxf(cmax, __shfl_xor(cmax, 32));
        float nm = fmaxf(m, cmax);
        float sc = __expf(m - nm);             // lane-local (first iter: exp(-inf)=0)
        float p1 = v1 ? __expf(e1 - nm) : 0.f;
        float p2 = v2 ? __expf(e2 - nm) : 0.f;
        float cs = p1 + p2;
        cs += __shfl_xor(cs, 16);
        cs += __shfl_xor(cs, 32);
        den = den * sc + cs;
        m = nm;
        #pragma unroll
        for (int k = 0; k < 8; ++k) acc[k] *= sc;
        if (v1) ACC_EDGE(h1, p1)
        if (v2) ACC_EDGE(h2, p2)
    }
    // combine the four edge-slot accumulators
    #pragma unroll
    for (int off = 16; off < 64; off <<= 1) {
        #pragma unroll
        for (int k = 0; k < 8; ++k) acc[k] += __shfl_xor(acc[k], off);
    }
    if (lane < 16) {
        float inv = 1.f / den;                 // den already per-head, lane-local
        float o[8];
        #pragma unroll
        for (int k = 0; k < 8; ++k) {
            o[k] = acc[k] * inv + bias[cl * 8 + k];
            if (RELU) o[k] = fmaxf(o[k], 0.f);
        }
        if (OUTBF) {
            uint4 ov;
            ov.x = (unsigned)f2bf(o[0]) | ((unsigned)f2bf(o[1]) << 16);
            ov.y = (unsigned)f2bf(o[2]) | ((unsigned)f2bf(o[3]) << 16);
            ov.z = (unsigned)f2bf(o[4]) | ((unsigned)f2bf(o[5]) << 16);
            ov.w = (unsigned)f2bf(o[6]) | ((unsigned)f2bf(o[7]) << 16);
            *(uint4*)&((ushort*)outv)[(size_t)node * HID + cl * 8] = ov;
        } else {
            float* op = &((float*)outv)[(size_t)node * HID + cl * 8];
            *(float4*)op = make_float4(o[0], o[1], o[2], o[3]);
            *(float4*)(op + 4) = make_float4(o[4], o[5], o[6], o[7]);
        }
    }
    #undef ACC_EDGE
}

// ---------------- launch ----------------

extern "C" void kernel_launch(void* const* d_in, const int* in_sizes, int n_in,
                              void* d_out, int out_size, void* d_ws, size_t ws_size,
                              hipStream_t stream) {
    const float* x   = (const float*)d_in[0];
    const int*   ei  = (const int*)d_in[1];
    const float* W1  = (const float*)d_in[2];
    const float* as1 = (const float*)d_in[3];
    const float* ad1 = (const float*)d_in[4];
    const float* b1  = (const float*)d_in[5];
    const float* W2  = (const float*)d_in[6];
    const float* as2 = (const float*)d_in[7];
    const float* ad2 = (const float*)d_in[8];
    const float* b2  = (const float*)d_in[9];
    const float* W3  = (const float*)d_in[10];
    const float* as3 = (const float*)d_in[11];
    const float* ad3 = (const float*)d_in[12];
    const float* b3  = (const float*)d_in[13];

    int N = in_sizes[0] / HID;
    int E = in_sizes[1] / 2;
    const int* srcv = ei;
    const int* dstv = ei + E;

    char* ws = (char*)d_ws;
    size_t ofs = 0;
    auto alloc = [&](size_t bytes) -> void* {
        void* p = ws + ofs;
        ofs = (ofs + bytes + 255) & ~(size_t)255;
        return p;
    };
    int NB = (N + 255) / 256;
    int*    rp   = (int*)alloc((size_t)(N + 1) * 4);
    int*    cur  = (int*)alloc((size_t)N * 4);
    int*    deg  = (int*)alloc((size_t)N * 4);
    int*    bsum = (int*)alloc((size_t)NB * 4);
    int*    boff = (int*)alloc((size_t)NB * 4);
    int*    col  = (int*)alloc((size_t)(E + N) * 4);
    ushort* ys   = (ushort*)alloc((size_t)N * HID * 2);   // layer-1 out (bf16)
    ushort* zs   = (ushort*)alloc((size_t)N * HID * 2);   // layer-2 out (bf16)
    ushort* hb   = (ushort*)alloc((size_t)N * HID * 2);   // per-layer h (bf16)
    ushort* wbuf = (ushort*)alloc((size_t)3 * 32768 * 2); // W frag layout (hi+lo) x3
    float*  pa   = (float*)alloc((size_t)N * 4 * 4);
    float*  pd   = (float*)alloc((size_t)N * 4 * 4);

    // CSR build
    deg_init_kernel<<<(N + 255) / 256, 256, 0, stream>>>(deg, N);
    deg_count_kernel<<<(E + 255) / 256, 256, 0, stream>>>(dstv, E, deg);
    scan1_kernel<<<NB, 256, 0, stream>>>(deg, bsum, N);
    scan2_kernel<<<1, 256, 0, stream>>>(bsum, boff, rp, NB, N);
    scan3_kernel<<<NB, 256, 0, stream>>>(deg, boff, rp, cur, col, N);
    scatter_kernel<<<(E + 255) / 256, 256, 0, stream>>>(srcv, dstv, E, cur, col);

    prep_w_kernel<<<(3 * 4096 + 255) / 256, 256, 0, stream>>>(W1, W2, W3, wbuf);

    int gGemm = (N + 63) / 64;
    int gWave = (N + 3) / 4;

    // layer 1 (4 heads, relu): fp32 x in -> ys
    mfma_gemm_kernel<4, true><<<gGemm, 256, 0, stream>>>(x, wbuf, as1, ad1, hb, pa, pd, N);
    aggregate_kernel<4, true, true><<<gWave, 256, 0, stream>>>(hb, pa, pd, rp, col, b1, ys, N);
    // layer 2 (4 heads, relu) -> zs
    mfma_gemm_kernel<4, false><<<gGemm, 256, 0, stream>>>(ys, wbuf + 32768, as2, ad2, hb, pa, pd, N);
    aggregate_kernel<4, true, true><<<gWave, 256, 0, stream>>>(hb, pa, pd, rp, col, b2, zs, N);
    // layer 3 (1 head, no relu) -> d_out fp32
    mfma_gemm_kernel<1, false><<<gGemm, 256, 0, stream>>>(zs, wbuf + 65536, as3, ad3, hb, pa, pd, N);
    aggregate_kernel<1, false, false><<<gWave, 256, 0, stream>>>(hb, pa, pd, rp, col, b3, d_out, N);
}

// Round 10
// 196.810 us; speedup vs baseline: 1.4855x; 1.1184x over previous
//
#include <hip/hip_runtime.h>
#include <hip/hip_bf16.h>

#define HID 128

typedef __attribute__((ext_vector_type(8))) short bf16x8;
typedef __attribute__((ext_vector_type(4))) float f32x4;

__device__ inline unsigned short f2bf(float f) {
    unsigned u = __float_as_uint(f);
    u += 0x7fffu + ((u >> 16) & 1u);   // RNE
    return (unsigned short)(u >> 16);
}
__device__ inline float bfval(unsigned short s) {
    return __uint_as_float(((unsigned)s) << 16);
}
__device__ inline float bflo(unsigned u) { return __uint_as_float(u << 16); }
__device__ inline float bfhi(unsigned u) { return __uint_as_float(u & 0xffff0000u); }

// ---------------- CSR build ----------------

__global__ void deg_init_kernel(int* deg, int N) {
    int i = blockIdx.x * blockDim.x + threadIdx.x;
    if (i < N) deg[i] = 1;  // self loop
}

__global__ void deg_count_kernel(const int* __restrict__ dst, int E, int* deg) {
    int i = blockIdx.x * blockDim.x + threadIdx.x;
    if (i < E) atomicAdd(&deg[dst[i]], 1);
}

__global__ __launch_bounds__(256) void scan1_kernel(const int* __restrict__ deg,
                                                    int* __restrict__ bsum, int N) {
    int tid = threadIdx.x;
    int i = blockIdx.x * 256 + tid;
    int v = (i < N) ? deg[i] : 0;
    #pragma unroll
    for (int off = 1; off < 64; off <<= 1) v += __shfl_xor(v, off);
    __shared__ int ws[4];
    if ((tid & 63) == 0) ws[tid >> 6] = v;
    __syncthreads();
    if (tid == 0) bsum[blockIdx.x] = ws[0] + ws[1] + ws[2] + ws[3];
}

__global__ __launch_bounds__(256) void scan2_kernel(const int* __restrict__ bsum,
                                                    int* __restrict__ boff,
                                                    int* __restrict__ row_ptr, int NB, int N) {
    __shared__ int s[256];
    int tid = threadIdx.x;
    int v = (tid < NB) ? bsum[tid] : 0;
    s[tid] = v;
    __syncthreads();
    for (int off = 1; off < 256; off <<= 1) {
        int t = (tid >= off) ? s[tid - off] : 0;
        __syncthreads();
        s[tid] += t;
        __syncthreads();
    }
    if (tid < NB) boff[tid] = s[tid] - v;  // exclusive
    if (tid == NB - 1) row_ptr[N] = s[tid];
}

__global__ __launch_bounds__(256) void scan3_kernel(const int* __restrict__ deg,
                                                    const int* __restrict__ boff,
                                                    int* __restrict__ row_ptr,
                                                    int* __restrict__ cursor,
                                                    int* __restrict__ col, int N) {
    __shared__ int s[256];
    int tid = threadIdx.x;
    int i = blockIdx.x * 256 + tid;
    int d = (i < N) ? deg[i] : 0;
    s[tid] = d;
    __syncthreads();
    for (int off = 1; off < 256; off <<= 1) {
        int t = (tid >= off) ? s[tid - off] : 0;
        __syncthreads();
        s[tid] += t;
        __syncthreads();
    }
    if (i < N) {
        int run = boff[blockIdx.x] + s[tid] - d;  // exclusive prefix
        row_ptr[i] = run;
        cursor[i] = run + 1;  // slot 0 taken by self loop
        col[run] = i;         // self loop
    }
}

__global__ void scatter_kernel(const int* __restrict__ src, const int* __restrict__ dst,
                               int E, int* cursor, int* col) {
    int i = blockIdx.x * blockDim.x + threadIdx.x;
    if (i < E) {
        int pos = atomicAdd(&cursor[dst[i]], 1);
        col[pos] = src[i];
    }
}

// ---------------- prep: W -> MFMA frag layout, hi/lo split ----------------
// wbuf[layer][p][s][t][lane][j]  (ushort), p=0: bf16(W), p=1: bf16(W - hi)
// frag element j for lane l: k = s*32 + (l>>4)*8 + j, c = t*16 + (l&15)
__global__ void prep_w_kernel(const float* __restrict__ W1, const float* __restrict__ W2,
                              const float* __restrict__ W3, ushort* __restrict__ wbuf) {
    int t = blockIdx.x * blockDim.x + threadIdx.x;   // 0 .. 3*4096-1
    if (t >= 3 * 4096) return;
    int layer = t >> 12;
    int rem = t & 4095;
    int lane = rem & 63;
    int tt = (rem >> 6) & 7;
    int s = (rem >> 9) & 3;
    int p = rem >> 11;
    const float* W = (layer == 0) ? W1 : (layer == 1) ? W2 : W3;
    int k0 = s * 32 + (lane >> 4) * 8;
    int c = tt * 16 + (lane & 15);
    ushort out[8];
    #pragma unroll
    for (int j = 0; j < 8; ++j) {
        float w = W[(size_t)(k0 + j) * HID + c];
        unsigned short hi = f2bf(w);
        out[j] = (p == 0) ? hi : f2bf(w - bfval(hi));
    }
    size_t base = (size_t)layer * 32768 + ((((size_t)p * 4 + s) * 8 + tt) * 64 + lane) * 8;
    *(uint4*)&wbuf[base] = *(uint4*)out;
}

// ---------------- MFMA GEMM + fused alphas (W as A-operand, LDS-staged W) ----------------
// block = 256 thr = 4 waves, 64 rows (16/wave). Full W (hi+lo frags, 64 KB) in LDS.
// D layout: col(lane&15) = node row, row((lane>>4)*4+j) = out-channel within tile.
template <int H, bool SRC32>
__global__ __launch_bounds__(256) void mfma_gemm_kernel(const void* __restrict__ xin,
                                                        const ushort* __restrict__ wbuf,
                                                        const float* __restrict__ a_src,
                                                        const float* __restrict__ a_dst,
                                                        ushort* __restrict__ h,
                                                        float* __restrict__ pa_out,
                                                        float* __restrict__ pd_out, int N) {
    __shared__ ushort wl[32768];   // 64 KB
    int tid = threadIdx.x;
    #pragma unroll
    for (int t = 0; t < 16; ++t) {
        int i = (t * 256 + tid) * 8;
        *(uint4*)&wl[i] = *(const uint4*)&wbuf[i];
    }
    int wv = tid >> 6, lane = tid & 63;
    int r0 = blockIdx.x * 64 + wv * 16;
    int koff = (lane >> 4) * 8;

    // B-frag = x rows r0..r0+15 (N-index = lane&15), K = koff + s*32 + j
    int lrow = r0 + (lane & 15);
    if (lrow >= N) lrow = N - 1;
    bf16x8 xfrag[4];
    if (SRC32) {
        const float* xp = &((const float*)xin)[(size_t)lrow * HID + koff];
        #pragma unroll
        for (int s = 0; s < 4; ++s) {
            float4 a = *(const float4*)&xp[s * 32];
            float4 b = *(const float4*)&xp[s * 32 + 4];
            ushort u[8] = {f2bf(a.x), f2bf(a.y), f2bf(a.z), f2bf(a.w),
                           f2bf(b.x), f2bf(b.y), f2bf(b.z), f2bf(b.w)};
            xfrag[s] = *(bf16x8*)u;
        }
    } else {
        const ushort* xp = &((const ushort*)xin)[(size_t)lrow * HID + koff];
        #pragma unroll
        for (int s = 0; s < 4; ++s) xfrag[s] = *(const bf16x8*)&xp[s * 32];
    }
    __syncthreads();

    f32x4 acc[8];
    #pragma unroll
    for (int t = 0; t < 8; ++t) acc[t] = (f32x4){0.f, 0.f, 0.f, 0.f};

    #pragma unroll
    for (int p = 0; p < 2; ++p)
        #pragma unroll
        for (int s = 0; s < 4; ++s)
            #pragma unroll
            for (int t = 0; t < 8; ++t) {
                bf16x8 w = *(const bf16x8*)&wl[((((p * 4 + s) * 8) + t) * 64 + lane) * 8];
                acc[t] = __builtin_amdgcn_mfma_f32_16x16x32_bf16(w, xfrag[s], acc[t], 0, 0, 0);
            }

    // epilogue
    int row = r0 + (lane & 15);
    int cg  = lane >> 4;              // channel group: ch = t*16 + cg*4 + j
    bool rowok = row < N;

    if (rowok) {
        #pragma unroll
        for (int t = 0; t < 8; ++t) {
            uint2 pk;
            pk.x = (unsigned)f2bf(acc[t][0]) | ((unsigned)f2bf(acc[t][1]) << 16);
            pk.y = (unsigned)f2bf(acc[t][2]) | ((unsigned)f2bf(acc[t][3]) << 16);
            *(uint2*)&h[(size_t)row * HID + t * 16 + cg * 4] = pk;
        }
    }

    if (H == 4) {
        float pah[4], pdh[4];
        #pragma unroll
        for (int hd = 0; hd < 4; ++hd) {
            float sa = 0.f, sd = 0.f;
            #pragma unroll
            for (int tt = 0; tt < 2; ++tt) {
                int t = 2 * hd + tt;
                float4 av = *(const float4*)&a_src[t * 16 + cg * 4];
                float4 dv = *(const float4*)&a_dst[t * 16 + cg * 4];
                sa += acc[t][0] * av.x + acc[t][1] * av.y + acc[t][2] * av.z + acc[t][3] * av.w;
                sd += acc[t][0] * dv.x + acc[t][1] * dv.y + acc[t][2] * dv.z + acc[t][3] * dv.w;
            }
            pah[hd] = sa; pdh[hd] = sd;
        }
        #pragma unroll
        for (int off = 16; off < 64; off <<= 1)
            #pragma unroll
            for (int hd = 0; hd < 4; ++hd) {
                pah[hd] += __shfl_xor(pah[hd], off);
                pdh[hd] += __shfl_xor(pdh[hd], off);
            }
        if (rowok && cg == 0) {
            #pragma unroll
            for (int hd = 0; hd < 4; ++hd) {
                pa_out[(size_t)row * 4 + hd] = pah[hd];
                pd_out[(size_t)row * 4 + hd] = pdh[hd];
            }
        }
    } else {
        float sa = 0.f, sd = 0.f;
        #pragma unroll
        for (int t = 0; t < 8; ++t) {
            float4 av = *(const float4*)&a_src[t * 16 + cg * 4];
            float4 dv = *(const float4*)&a_dst[t * 16 + cg * 4];
            sa += acc[t][0] * av.x + acc[t][1] * av.y + acc[t][2] * av.z + acc[t][3] * av.w;
            sd += acc[t][0] * dv.x + acc[t][1] * dv.y + acc[t][2] * dv.z + acc[t][3] * dv.w;
        }
        #pragma unroll
        for (int off = 16; off < 64; off <<= 1) {
            sa += __shfl_xor(sa, 16 == off ? 16 : 32);
            sd += __shfl_xor(sd, 16 == off ? 16 : 32);
        }
        if (rowok && cg == 0) { pa_out[row] = sa; pd_out[row] = sd; }
    }
}

// ---------------- aggregation: ZERO-shuffle, 16-lane group per node ----------------
// wave = 4 nodes. Lane = g*16 + cl: group g owns node, lane owns channels cl*8..cl*8+7
// AND head ahd = cl>>2's softmax state (m, den lane-local). No cross-lane ops in the
// loop; only 2 shfl_xor once for the wave-uniform trip count.
template <int H, bool RELU, bool OUTBF>
__global__ __launch_bounds__(256) void aggregate_kernel(const ushort* __restrict__ h,
                                                        const float* __restrict__ asrc,
                                                        const float* __restrict__ adst,
                                                        const int* __restrict__ rp,
                                                        const int* __restrict__ col,
                                                        const float* __restrict__ bias,
                                                        void* __restrict__ outv, int N) {
    int lane = threadIdx.x & 63;
    int wid  = blockIdx.x * 4 + (threadIdx.x >> 6);
    int g  = lane >> 4;
    int cl = lane & 15;
    int node = wid * 4 + g;
    bool active = node < N;
    int nd = active ? node : N - 1;
    int start = rp[nd], end = rp[nd + 1];
    int deg = end - start;                 // >= 1 (self loop)
    int dmax = deg;
    dmax = max(dmax, __shfl_xor(dmax, 16));
    dmax = max(dmax, __shfl_xor(dmax, 32));
    int ahd = (H == 4) ? (cl >> 2) : 0;
    float adst_n = adst[(size_t)nd * H + ahd];

    float m = -INFINITY, den = 0.f;
    float acc[8] = {0.f, 0.f, 0.f, 0.f, 0.f, 0.f, 0.f, 0.f};

    for (int it = 0; it < dmax; it += 2) {
        bool v1 = it < deg, v2 = (it + 1) < deg;
        int s1 = v1 ? col[start + it] : 0;
        int s2 = v2 ? col[start + it + 1] : 0;
        uint4 h1, h2;
        if (v1) h1 = *(const uint4*)&h[(size_t)s1 * HID + cl * 8];
        if (v2) h2 = *(const uint4*)&h[(size_t)s2 * HID + cl * 8];
        float e1 = -INFINITY, e2 = -INFINITY;
        if (v1) { float t = asrc[(size_t)s1 * H + ahd] + adst_n; e1 = (t >= 0.f) ? t : 0.2f * t; }
        if (v2) { float t = asrc[(size_t)s2 * H + ahd] + adst_n; e2 = (t >= 0.f) ? t : 0.2f * t; }
        float nm = fmaxf(m, fmaxf(e1, e2));
        float sc = __expf(m - nm);         // first iter: exp(-inf)=0; done-group: 1
        float p1 = v1 ? __expf(e1 - nm) : 0.f;
        float p2 = v2 ? __expf(e2 - nm) : 0.f;
        den = den * sc + (p1 + p2);
        m = nm;
        acc[0] = acc[0] * sc + p1 * bflo(h1.x) + p2 * bflo(h2.x);
        acc[1] = acc[1] * sc + p1 * bfhi(h1.x) + p2 * bfhi(h2.x);
        acc[2] = acc[2] * sc + p1 * bflo(h1.y) + p2 * bflo(h2.y);
        acc[3] = acc[3] * sc + p1 * bfhi(h1.y) + p2 * bfhi(h2.y);
        acc[4] = acc[4] * sc + p1 * bflo(h1.z) + p2 * bflo(h2.z);
        acc[5] = acc[5] * sc + p1 * bfhi(h1.z) + p2 * bfhi(h2.z);
        acc[6] = acc[6] * sc + p1 * bflo(h1.w) + p2 * bflo(h2.w);
        acc[7] = acc[7] * sc + p1 * bfhi(h1.w) + p2 * bfhi(h2.w);
    }

    if (active) {
        float inv = 1.f / den;
        float o[8];
        #pragma unroll
        for (int k = 0; k < 8; ++k) {
            o[k] = acc[k] * inv + bias[cl * 8 + k];
            if (RELU) o[k] = fmaxf(o[k], 0.f);
        }
        if (OUTBF) {
            uint4 ov;
            ov.x = (unsigned)f2bf(o[0]) | ((unsigned)f2bf(o[1]) << 16);
            ov.y = (unsigned)f2bf(o[2]) | ((unsigned)f2bf(o[3]) << 16);
            ov.z = (unsigned)f2bf(o[4]) | ((unsigned)f2bf(o[5]) << 16);
            ov.w = (unsigned)f2bf(o[6]) | ((unsigned)f2bf(o[7]) << 16);
            *(uint4*)&((ushort*)outv)[(size_t)node * HID + cl * 8] = ov;
        } else {
            float* op = &((float*)outv)[(size_t)node * HID + cl * 8];
            *(float4*)op = make_float4(o[0], o[1], o[2], o[3]);
            *(float4*)(op + 4) = make_float4(o[4], o[5], o[6], o[7]);
        }
    }
}

// ---------------- launch ----------------

extern "C" void kernel_launch(void* const* d_in, const int* in_sizes, int n_in,
                              void* d_out, int out_size, void* d_ws, size_t ws_size,
                              hipStream_t stream) {
    const float* x   = (const float*)d_in[0];
    const int*   ei  = (const int*)d_in[1];
    const float* W1  = (const float*)d_in[2];
    const float* as1 = (const float*)d_in[3];
    const float* ad1 = (const float*)d_in[4];
    const float* b1  = (const float*)d_in[5];
    const float* W2  = (const float*)d_in[6];
    const float* as2 = (const float*)d_in[7];
    const float* ad2 = (const float*)d_in[8];
    const float* b2  = (const float*)d_in[9];
    const float* W3  = (const float*)d_in[10];
    const float* as3 = (const float*)d_in[11];
    const float* ad3 = (const float*)d_in[12];
    const float* b3  = (const float*)d_in[13];

    int N = in_sizes[0] / HID;
    int E = in_sizes[1] / 2;
    const int* srcv = ei;
    const int* dstv = ei + E;

    char* ws = (char*)d_ws;
    size_t ofs = 0;
    auto alloc = [&](size_t bytes) -> void* {
        void* p = ws + ofs;
        ofs = (ofs + bytes + 255) & ~(size_t)255;
        return p;
    };
    int NB = (N + 255) / 256;
    int*    rp   = (int*)alloc((size_t)(N + 1) * 4);
    int*    cur  = (int*)alloc((size_t)N * 4);
    int*    deg  = (int*)alloc((size_t)N * 4);
    int*    bsum = (int*)alloc((size_t)NB * 4);
    int*    boff = (int*)alloc((size_t)NB * 4);
    int*    col  = (int*)alloc((size_t)(E + N) * 4);
    ushort* ys   = (ushort*)alloc((size_t)N * HID * 2);   // layer-1 out (bf16)
    ushort* zs   = (ushort*)alloc((size_t)N * HID * 2);   // layer-2 out (bf16)
    ushort* hb   = (ushort*)alloc((size_t)N * HID * 2);   // per-layer h (bf16)
    ushort* wbuf = (ushort*)alloc((size_t)3 * 32768 * 2); // W frag layout (hi+lo) x3
    float*  pa   = (float*)alloc((size_t)N * 4 * 4);
    float*  pd   = (float*)alloc((size_t)N * 4 * 4);

    // CSR build
    deg_init_kernel<<<(N + 255) / 256, 256, 0, stream>>>(deg, N);
    deg_count_kernel<<<(E + 255) / 256, 256, 0, stream>>>(dstv, E, deg);
    scan1_kernel<<<NB, 256, 0, stream>>>(deg, bsum, N);
    scan2_kernel<<<1, 256, 0, stream>>>(bsum, boff, rp, NB, N);
    scan3_kernel<<<NB, 256, 0, stream>>>(deg, boff, rp, cur, col, N);
    scatter_kernel<<<(E + 255) / 256, 256, 0, stream>>>(srcv, dstv, E, cur, col);

    prep_w_kernel<<<(3 * 4096 + 255) / 256, 256, 0, stream>>>(W1, W2, W3, wbuf);

    int gGemm = (N + 63) / 64;
    int gWave = (N + 15) / 16;   // 4 nodes per wave, 4 waves per block

    // layer 1 (4 heads, relu): fp32 x in -> ys
    mfma_gemm_kernel<4, true><<<gGemm, 256, 0, stream>>>(x, wbuf, as1, ad1, hb, pa, pd, N);
    aggregate_kernel<4, true, true><<<gWave, 256, 0, stream>>>(hb, pa, pd, rp, col, b1, ys, N);
    // layer 2 (4 heads, relu) -> zs
    mfma_gemm_kernel<4, false><<<gGemm, 256, 0, stream>>>(ys, wbuf + 32768, as2, ad2, hb, pa, pd, N);
    aggregate_kernel<4, true, true><<<gWave, 256, 0, stream>>>(hb, pa, pd, rp, col, b2, zs, N);
    // layer 3 (1 head, no relu) -> d_out fp32
    mfma_gemm_kernel<1, false><<<gGemm, 256, 0, stream>>>(zs, wbuf + 65536, as3, ad3, hb, pa, pd, N);
    aggregate_kernel<1, false, false><<<gWave, 256, 0, stream>>>(hb, pa, pd, rp, col, b3, d_out, N);
}

// Round 12
// 188.745 us; speedup vs baseline: 1.5489x; 1.0427x over previous
//
#include <hip/hip_runtime.h>
#include <hip/hip_bf16.h>

#define HID 128

typedef __attribute__((ext_vector_type(8))) short bf16x8;
typedef __attribute__((ext_vector_type(4))) float f32x4;

__device__ inline unsigned short f2bf(float f) {
    unsigned u = __float_as_uint(f);
    u += 0x7fffu + ((u >> 16) & 1u);   // RNE
    return (unsigned short)(u >> 16);
}
__device__ inline float bflo(unsigned u) { return __uint_as_float(u << 16); }
__device__ inline float bfhi(unsigned u) { return __uint_as_float(u & 0xffff0000u); }

// ---------------- CSR build ----------------

// fused: deg init (i < N) + W -> MFMA frag layout (i < 3*2048)
// wbuf[layer][s][t][lane][j] (ushort); frag elem j for lane l: k = s*32+(l>>4)*8+j, c = t*16+(l&15)
__global__ void init_kernel(const float* __restrict__ W1, const float* __restrict__ W2,
                            const float* __restrict__ W3, ushort* __restrict__ wbuf,
                            int* __restrict__ deg, int N) {
    int i = blockIdx.x * blockDim.x + threadIdx.x;
    if (i < N) deg[i] = 1;  // self loop
    if (i < 3 * 2048) {
        int layer = i >> 11;
        int rem = i & 2047;
        int lane = rem & 63;
        int tt = (rem >> 6) & 7;
        int s = rem >> 9;
        const float* W = (layer == 0) ? W1 : (layer == 1) ? W2 : W3;
        int k0 = s * 32 + (lane >> 4) * 8;
        int c = tt * 16 + (lane & 15);
        ushort out[8];
        #pragma unroll
        for (int j = 0; j < 8; ++j) out[j] = f2bf(W[(size_t)(k0 + j) * HID + c]);
        size_t base = (size_t)layer * 16384 + (((size_t)s * 8 + tt) * 64 + lane) * 8;
        *(uint4*)&wbuf[base] = *(uint4*)out;
    }
}

__global__ void deg_count_kernel(const int* __restrict__ dst, int E, int* deg) {
    int i = blockIdx.x * blockDim.x + threadIdx.x;
    if (i < E) atomicAdd(&deg[dst[i]], 1);
}

__global__ __launch_bounds__(256) void scan1_kernel(const int* __restrict__ deg,
                                                    int* __restrict__ bsum, int N) {
    int tid = threadIdx.x;
    int i = blockIdx.x * 256 + tid;
    int v = (i < N) ? deg[i] : 0;
    #pragma unroll
    for (int off = 1; off < 64; off <<= 1) v += __shfl_xor(v, off);
    __shared__ int ws[4];
    if ((tid & 63) == 0) ws[tid >> 6] = v;
    __syncthreads();
    if (tid == 0) bsum[blockIdx.x] = ws[0] + ws[1] + ws[2] + ws[3];
}

__global__ __launch_bounds__(256) void scan2_kernel(const int* __restrict__ bsum,
                                                    int* __restrict__ boff,
                                                    int* __restrict__ row_ptr, int NB, int N) {
    __shared__ int s[256];
    int tid = threadIdx.x;
    int v = (tid < NB) ? bsum[tid] : 0;
    s[tid] = v;
    __syncthreads();
    for (int off = 1; off < 256; off <<= 1) {
        int t = (tid >= off) ? s[tid - off] : 0;
        __syncthreads();
        s[tid] += t;
        __syncthreads();
    }
    if (tid < NB) boff[tid] = s[tid] - v;  // exclusive
    if (tid == NB - 1) row_ptr[N] = s[tid];
}

__global__ __launch_bounds__(256) void scan3_kernel(const int* __restrict__ deg,
                                                    const int* __restrict__ boff,
                                                    int* __restrict__ row_ptr,
                                                    int* __restrict__ cursor,
                                                    int* __restrict__ col, int N) {
    __shared__ int s[256];
    int tid = threadIdx.x;
    int i = blockIdx.x * 256 + tid;
    int d = (i < N) ? deg[i] : 0;
    s[tid] = d;
    __syncthreads();
    for (int off = 1; off < 256; off <<= 1) {
        int t = (tid >= off) ? s[tid - off] : 0;
        __syncthreads();
        s[tid] += t;
        __syncthreads();
    }
    if (i < N) {
        int run = boff[blockIdx.x] + s[tid] - d;  // exclusive prefix
        row_ptr[i] = run;
        cursor[i] = run + 1;  // slot 0 taken by self loop
        col[run] = i;         // self loop
    }
}

__global__ void scatter_kernel(const int* __restrict__ src, const int* __restrict__ dst,
                               int E, int* cursor, int* col) {
    int i = blockIdx.x * blockDim.x + threadIdx.x;
    if (i < E) {
        int pos = atomicAdd(&cursor[dst[i]], 1);
        col[pos] = src[i];
    }
}

// ---------------- MFMA GEMM + fused alphas (W as A-operand, 32 KB LDS W) ----------------
// block = 256 thr = 4 waves, 64 rows (16/wave). W frags (single bf16 pass) in LDS.
// D layout: col(lane&15) = node row, row((lane>>4)*4+j) = out-channel within tile.
template <int H, bool SRC32>
__global__ __launch_bounds__(256) void mfma_gemm_kernel(const void* __restrict__ xin,
                                                        const ushort* __restrict__ wbuf,
                                                        const float* __restrict__ a_src,
                                                        const float* __restrict__ a_dst,
                                                        ushort* __restrict__ h,
                                                        float* __restrict__ pa_out,
                                                        float* __restrict__ pd_out, int N) {
    __shared__ ushort wl[16384];   // 32 KB
    int tid = threadIdx.x;
    #pragma unroll
    for (int t = 0; t < 8; ++t) {
        int i = (t * 256 + tid) * 8;
        *(uint4*)&wl[i] = *(const uint4*)&wbuf[i];
    }
    int wv = tid >> 6, lane = tid & 63;
    int r0 = blockIdx.x * 64 + wv * 16;
    int koff = (lane >> 4) * 8;

    // B-frag = x rows r0..r0+15 (N-index = lane&15), K = koff + s*32 + j
    int lrow = r0 + (lane & 15);
    if (lrow >= N) lrow = N - 1;
    bf16x8 xfrag[4];
    if (SRC32) {
        const float* xp = &((const float*)xin)[(size_t)lrow * HID + koff];
        #pragma unroll
        for (int s = 0; s < 4; ++s) {
            float4 a = *(const float4*)&xp[s * 32];
            float4 b = *(const float4*)&xp[s * 32 + 4];
            ushort u[8] = {f2bf(a.x), f2bf(a.y), f2bf(a.z), f2bf(a.w),
                           f2bf(b.x), f2bf(b.y), f2bf(b.z), f2bf(b.w)};
            xfrag[s] = *(bf16x8*)u;
        }
    } else {
        const ushort* xp = &((const ushort*)xin)[(size_t)lrow * HID + koff];
        #pragma unroll
        for (int s = 0; s < 4; ++s) xfrag[s] = *(const bf16x8*)&xp[s * 32];
    }
    __syncthreads();

    f32x4 acc[8];
    #pragma unroll
    for (int t = 0; t < 8; ++t) acc[t] = (f32x4){0.f, 0.f, 0.f, 0.f};

    #pragma unroll
    for (int s = 0; s < 4; ++s)
        #pragma unroll
        for (int t = 0; t < 8; ++t) {
            bf16x8 w = *(const bf16x8*)&wl[(((s * 8) + t) * 64 + lane) * 8];
            acc[t] = __builtin_amdgcn_mfma_f32_16x16x32_bf16(w, xfrag[s], acc[t], 0, 0, 0);
        }

    // epilogue
    int row = r0 + (lane & 15);
    int cg  = lane >> 4;              // channel group: ch = t*16 + cg*4 + j
    bool rowok = row < N;

    if (rowok) {
        #pragma unroll
        for (int t = 0; t < 8; ++t) {
            uint2 pk;
            pk.x = (unsigned)f2bf(acc[t][0]) | ((unsigned)f2bf(acc[t][1]) << 16);
            pk.y = (unsigned)f2bf(acc[t][2]) | ((unsigned)f2bf(acc[t][3]) << 16);
            *(uint2*)&h[(size_t)row * HID + t * 16 + cg * 4] = pk;
        }
    }

    if (H == 4) {
        float pah[4], pdh[4];
        #pragma unroll
        for (int hd = 0; hd < 4; ++hd) {
            float sa = 0.f, sd = 0.f;
            #pragma unroll
            for (int tt = 0; tt < 2; ++tt) {
                int t = 2 * hd + tt;
                float4 av = *(const float4*)&a_src[t * 16 + cg * 4];
                float4 dv = *(const float4*)&a_dst[t * 16 + cg * 4];
                sa += acc[t][0] * av.x + acc[t][1] * av.y + acc[t][2] * av.z + acc[t][3] * av.w;
                sd += acc[t][0] * dv.x + acc[t][1] * dv.y + acc[t][2] * dv.z + acc[t][3] * dv.w;
            }
            pah[hd] = sa; pdh[hd] = sd;
        }
        #pragma unroll
        for (int off = 16; off < 64; off <<= 1)
            #pragma unroll
            for (int hd = 0; hd < 4; ++hd) {
                pah[hd] += __shfl_xor(pah[hd], off);
                pdh[hd] += __shfl_xor(pdh[hd], off);
            }
        if (rowok && cg == 0) {
            #pragma unroll
            for (int hd = 0; hd < 4; ++hd) {
                pa_out[(size_t)row * 4 + hd] = pah[hd];
                pd_out[(size_t)row * 4 + hd] = pdh[hd];
            }
        }
    } else {
        float sa = 0.f, sd = 0.f;
        #pragma unroll
        for (int t = 0; t < 8; ++t) {
            float4 av = *(const float4*)&a_src[t * 16 + cg * 4];
            float4 dv = *(const float4*)&a_dst[t * 16 + cg * 4];
            sa += acc[t][0] * av.x + acc[t][1] * av.y + acc[t][2] * av.z + acc[t][3] * av.w;
            sd += acc[t][0] * dv.x + acc[t][1] * dv.y + acc[t][2] * dv.z + acc[t][3] * dv.w;
        }
        sa += __shfl_xor(sa, 16); sa += __shfl_xor(sa, 32);
        sd += __shfl_xor(sd, 16); sd += __shfl_xor(sd, 32);
        if (rowok && cg == 0) { pa_out[row] = sa; pd_out[row] = sd; }
    }
}

// ---------------- aggregation: ZERO-shuffle, 16-lane group per node, 4-edge unroll ----------------
// wave = 4 nodes. Lane = g*16 + cl: group g owns node, lane owns channels cl*8..cl*8+7
// AND head ahd = cl>>2's softmax state (m, den lane-local). No cross-lane ops in the
// loop; only 2 shfl_xor once for the wave-uniform trip count.
// NOTE: invalid-slot gather registers MUST be zeroed — p*uninit = 0*Inf = NaN (R11 bug).
template <int H, bool RELU, bool OUTBF>
__global__ __launch_bounds__(256) void aggregate_kernel(const ushort* __restrict__ h,
                                                        const float* __restrict__ asrc,
                                                        const float* __restrict__ adst,
                                                        const int* __restrict__ rp,
                                                        const int* __restrict__ col,
                                                        const float* __restrict__ bias,
                                                        void* __restrict__ outv, int N) {
    int lane = threadIdx.x & 63;
    int wid  = blockIdx.x * 4 + (threadIdx.x >> 6);
    int g  = lane >> 4;
    int cl = lane & 15;
    int node = wid * 4 + g;
    bool active = node < N;
    int nd = active ? node : N - 1;
    int start = rp[nd], end = rp[nd + 1];
    int deg = end - start;                 // >= 1 (self loop)
    int dmax = deg;
    dmax = max(dmax, __shfl_xor(dmax, 16));
    dmax = max(dmax, __shfl_xor(dmax, 32));
    int ahd = (H == 4) ? (cl >> 2) : 0;
    float adst_n = adst[(size_t)nd * H + ahd];

    float m = -INFINITY, den = 0.f;
    float acc[8] = {0.f, 0.f, 0.f, 0.f, 0.f, 0.f, 0.f, 0.f};
    const uint4 zero4 = make_uint4(0u, 0u, 0u, 0u);

    for (int it = 0; it < dmax; it += 4) {
        bool v1 = it < deg, v2 = it + 1 < deg, v3 = it + 2 < deg, v4 = it + 3 < deg;
        int s1 = v1 ? col[start + it] : 0;
        int s2 = v2 ? col[start + it + 1] : 0;
        int s3 = v3 ? col[start + it + 2] : 0;
        int s4 = v4 ? col[start + it + 3] : 0;
        uint4 h1 = zero4, h2 = zero4, h3 = zero4, h4 = zero4;
        if (v1) h1 = *(const uint4*)&h[(size_t)s1 * HID + cl * 8];
        if (v2) h2 = *(const uint4*)&h[(size_t)s2 * HID + cl * 8];
        if (v3) h3 = *(const uint4*)&h[(size_t)s3 * HID + cl * 8];
        if (v4) h4 = *(const uint4*)&h[(size_t)s4 * HID + cl * 8];
        float e1 = -INFINITY, e2 = -INFINITY, e3 = -INFINITY, e4 = -INFINITY;
        if (v1) { float t = asrc[(size_t)s1 * H + ahd] + adst_n; e1 = (t >= 0.f) ? t : 0.2f * t; }
        if (v2) { float t = asrc[(size_t)s2 * H + ahd] + adst_n; e2 = (t >= 0.f) ? t : 0.2f * t; }
        if (v3) { float t = asrc[(size_t)s3 * H + ahd] + adst_n; e3 = (t >= 0.f) ? t : 0.2f * t; }
        if (v4) { float t = asrc[(size_t)s4 * H + ahd] + adst_n; e4 = (t >= 0.f) ? t : 0.2f * t; }
        float nm = fmaxf(fmaxf(m, fmaxf(e1, e2)), fmaxf(e3, e4));
        float sc = __expf(m - nm);         // first iter: exp(-inf)=0; done-group: 1
        float p1 = v1 ? __expf(e1 - nm) : 0.f;
        float p2 = v2 ? __expf(e2 - nm) : 0.f;
        float p3 = v3 ? __expf(e3 - nm) : 0.f;
        float p4 = v4 ? __expf(e4 - nm) : 0.f;
        den = den * sc + ((p1 + p2) + (p3 + p4));
        m = nm;
        acc[0] = acc[0] * sc + p1 * bflo(h1.x) + p2 * bflo(h2.x) + p3 * bflo(h3.x) + p4 * bflo(h4.x);
        acc[1] = acc[1] * sc + p1 * bfhi(h1.x) + p2 * bfhi(h2.x) + p3 * bfhi(h3.x) + p4 * bfhi(h4.x);
        acc[2] = acc[2] * sc + p1 * bflo(h1.y) + p2 * bflo(h2.y) + p3 * bflo(h3.y) + p4 * bflo(h4.y);
        acc[3] = acc[3] * sc + p1 * bfhi(h1.y) + p2 * bfhi(h2.y) + p3 * bfhi(h3.y) + p4 * bfhi(h4.y);
        acc[4] = acc[4] * sc + p1 * bflo(h1.z) + p2 * bflo(h2.z) + p3 * bflo(h3.z) + p4 * bflo(h4.z);
        acc[5] = acc[5] * sc + p1 * bfhi(h1.z) + p2 * bfhi(h2.z) + p3 * bfhi(h3.z) + p4 * bfhi(h4.z);
        acc[6] = acc[6] * sc + p1 * bflo(h1.w) + p2 * bflo(h2.w) + p3 * bflo(h3.w) + p4 * bflo(h4.w);
        acc[7] = acc[7] * sc + p1 * bfhi(h1.w) + p2 * bfhi(h2.w) + p3 * bfhi(h3.w) + p4 * bfhi(h4.w);
    }

    if (active) {
        float inv = 1.f / den;
        float o[8];
        #pragma unroll
        for (int k = 0; k < 8; ++k) {
            o[k] = acc[k] * inv + bias[cl * 8 + k];
            if (RELU) o[k] = fmaxf(o[k], 0.f);
        }
        if (OUTBF) {
            uint4 ov;
            ov.x = (unsigned)f2bf(o[0]) | ((unsigned)f2bf(o[1]) << 16);
            ov.y = (unsigned)f2bf(o[2]) | ((unsigned)f2bf(o[3]) << 16);
            ov.z = (unsigned)f2bf(o[4]) | ((unsigned)f2bf(o[5]) << 16);
            ov.w = (unsigned)f2bf(o[6]) | ((unsigned)f2bf(o[7]) << 16);
            *(uint4*)&((ushort*)outv)[(size_t)node * HID + cl * 8] = ov;
        } else {
            float* op = &((float*)outv)[(size_t)node * HID + cl * 8];
            *(float4*)op = make_float4(o[0], o[1], o[2], o[3]);
            *(float4*)(op + 4) = make_float4(o[4], o[5], o[6], o[7]);
        }
    }
}

// ---------------- launch ----------------

extern "C" void kernel_launch(void* const* d_in, const int* in_sizes, int n_in,
                              void* d_out, int out_size, void* d_ws, size_t ws_size,
                              hipStream_t stream) {
    const float* x   = (const float*)d_in[0];
    const int*   ei  = (const int*)d_in[1];
    const float* W1  = (const float*)d_in[2];
    const float* as1 = (const float*)d_in[3];
    const float* ad1 = (const float*)d_in[4];
    const float* b1  = (const float*)d_in[5];
    const float* W2  = (const float*)d_in[6];
    const float* as2 = (const float*)d_in[7];
    const float* ad2 = (const float*)d_in[8];
    const float* b2  = (const float*)d_in[9];
    const float* W3  = (const float*)d_in[10];
    const float* as3 = (const float*)d_in[11];
    const float* ad3 = (const float*)d_in[12];
    const float* b3  = (const float*)d_in[13];

    int N = in_sizes[0] / HID;
    int E = in_sizes[1] / 2;
    const int* srcv = ei;
    const int* dstv = ei + E;

    char* ws = (char*)d_ws;
    size_t ofs = 0;
    auto alloc = [&](size_t bytes) -> void* {
        void* p = ws + ofs;
        ofs = (ofs + bytes + 255) & ~(size_t)255;
        return p;
    };
    int NB = (N + 255) / 256;
    int*    rp   = (int*)alloc((size_t)(N + 1) * 4);
    int*    cur  = (int*)alloc((size_t)N * 4);
    int*    deg  = (int*)alloc((size_t)N * 4);
    int*    bsum = (int*)alloc((size_t)NB * 4);
    int*    boff = (int*)alloc((size_t)NB * 4);
    int*    col  = (int*)alloc((size_t)(E + N) * 4);
    ushort* ys   = (ushort*)alloc((size_t)N * HID * 2);   // layer-1 out (bf16)
    ushort* zs   = (ushort*)alloc((size_t)N * HID * 2);   // layer-2 out (bf16)
    ushort* hb   = (ushort*)alloc((size_t)N * HID * 2);   // per-layer h (bf16)
    ushort* wbuf = (ushort*)alloc((size_t)3 * 16384 * 2); // W frag layout x3
    float*  pa   = (float*)alloc((size_t)N * 4 * 4);
    float*  pd   = (float*)alloc((size_t)N * 4 * 4);

    // CSR build + W prep
    init_kernel<<<(N + 255) / 256, 256, 0, stream>>>(W1, W2, W3, wbuf, deg, N);
    deg_count_kernel<<<(E + 255) / 256, 256, 0, stream>>>(dstv, E, deg);
    scan1_kernel<<<NB, 256, 0, stream>>>(deg, bsum, N);
    scan2_kernel<<<1, 256, 0, stream>>>(bsum, boff, rp, NB, N);
    scan3_kernel<<<NB, 256, 0, stream>>>(deg, boff, rp, cur, col, N);
    scatter_kernel<<<(E + 255) / 256, 256, 0, stream>>>(srcv, dstv, E, cur, col);

    int gGemm = (N + 63) / 64;
    int gWave = (N + 15) / 16;   // 4 nodes per wave, 4 waves per block

    // layer 1 (4 heads, relu): fp32 x in -> ys
    mfma_gemm_kernel<4, true><<<gGemm, 256, 0, stream>>>(x, wbuf, as1, ad1, hb, pa, pd, N);
    aggregate_kernel<4, true, true><<<gWave, 256, 0, stream>>>(hb, pa, pd, rp, col, b1, ys, N);
    // layer 2 (4 heads, relu) -> zs
    mfma_gemm_kernel<4, false><<<gGemm, 256, 0, stream>>>(ys, wbuf + 16384, as2, ad2, hb, pa, pd, N);
    aggregate_kernel<4, true, true><<<gWave, 256, 0, stream>>>(hb, pa, pd, rp, col, b2, zs, N);
    // layer 3 (1 head, no relu) -> d_out fp32
    mfma_gemm_kernel<1, false><<<gGemm, 256, 0, stream>>>(zs, wbuf + 32768, as3, ad3, hb, pa, pd, N);
    aggregate_kernel<1, false, false><<<gWave, 256, 0, stream>>>(hb, pa, pd, rp, col, b3, d_out, N);
}